// Round 11
// baseline (562.895 us; speedup 1.0000x reference)
//
#include <hip/hip_runtime.h>
#include <math.h>

#define NN 100000
#define NE 1600000
#define HID 64
#define NBE 2048                 // edge_agg blocks per side
#define NBG 2048                 // normgemm blocks per side
#define NBF 2048                 // normfinal blocks
#define EPB 2048                 // edges per bucket-build block
#define NBLK 782                 // ceil(NE/EPB)
#define NBUCK 98                 // ceil(NN/1024), bucket = dst>>10
#define MATN (2 * NBUCK * NBLK)  // count-matrix entries (both lists)
#define ESHIFT 30.0f             // fixed exponent shift: w = exp(e - ESHIFT)

typedef float f32x4 __attribute__((ext_vector_type(4)));
typedef int   i32x4 __attribute__((ext_vector_type(4)));

// ================= CSR build: two-level bucket partition =================
__global__ void bucket_hist(const int* __restrict__ eiS, const int* __restrict__ eiT,
                            int* __restrict__ cnt) {
    __shared__ int hist[NBUCK];
    int t = threadIdx.x;
    int side = blockIdx.x >= NBLK;
    int blk = blockIdx.x - side * NBLK;
    const i32x4* dst4 = (const i32x4*)((side ? eiT : eiS) + NE);
    if (t < NBUCK) hist[t] = 0;
    __syncthreads();
    int base4 = blk * (EPB / 4);
    #pragma unroll
    for (int k = 0; k < EPB / 1024; k++) {       // 2 iters of 256 int4
        int i4 = base4 + k * 256 + t;
        if (i4 < NE / 4) {
            i32x4 d = __builtin_nontemporal_load(&dst4[i4]);
            atomicAdd(&hist[d.x >> 10], 1);
            atomicAdd(&hist[d.y >> 10], 1);
            atomicAdd(&hist[d.z >> 10], 1);
            atomicAdd(&hist[d.w >> 10], 1);
        }
    }
    __syncthreads();
    if (t < NBUCK) cnt[side * (NBUCK * NBLK) + t * NBLK + blk] = hist[t];
}

__global__ void scanA(const int* __restrict__ deg, int* __restrict__ rowtmp,
                      int* __restrict__ bsum, int n) {
    __shared__ int sh[256];
    int t = threadIdx.x;
    int base = blockIdx.x * 1024 + t * 4;
    int a0 = (base + 0 < n) ? deg[base + 0] : 0;
    int a1 = (base + 1 < n) ? deg[base + 1] : 0;
    int a2 = (base + 2 < n) ? deg[base + 2] : 0;
    int a3 = (base + 3 < n) ? deg[base + 3] : 0;
    int s = a0 + a1 + a2 + a3;
    sh[t] = s;
    __syncthreads();
    for (int off = 1; off < 256; off <<= 1) {
        int x = (t >= off) ? sh[t - off] : 0;
        __syncthreads();
        sh[t] += x;
        __syncthreads();
    }
    int excl = sh[t] - s;
    if (t == 255) bsum[blockIdx.x] = sh[255];
    if (base + 0 < n) rowtmp[base + 0] = excl;
    if (base + 1 < n) rowtmp[base + 1] = excl + a0;
    if (base + 2 < n) rowtmp[base + 2] = excl + a0 + a1;
    if (base + 3 < n) rowtmp[base + 3] = excl + a0 + a1 + a2;
}

// scanB + prep4 fused (single-block kernel)
__global__ void scanB(int* __restrict__ bsum, int nb,
                      const float* __restrict__ a0, const float* __restrict__ a1,
                      const float* __restrict__ a2, const float* __restrict__ a3,
                      float* __restrict__ sum_a) {
    __shared__ int sh[256];
    int t = threadIdx.x;
    int v = (t < nb) ? bsum[t] : 0;
    sh[t] = v;
    __syncthreads();
    for (int off = 1; off < 256; off <<= 1) {
        int x = (t >= off) ? sh[t - off] : 0;
        __syncthreads();
        sh[t] += x;
        __syncthreads();
    }
    if (t < nb) bsum[t] = sh[t] - v; // exclusive
    // ---- prep4: sum of each attention vector (128 elems) ----
    int w = t >> 6, lane = t & 63;
    const float* a = (w == 0) ? a0 : (w == 1) ? a1 : (w == 2) ? a2 : a3;
    float av = a[lane] + a[lane + 64];
    #pragma unroll
    for (int o = 32; o >= 1; o >>= 1) av += __shfl_xor(av, o);
    if (lane == 0) sum_a[w] = av;
}

__global__ void scanC(const int* __restrict__ rowtmp, const int* __restrict__ bsum,
                      int* __restrict__ outp, int n, int total) {
    int i = blockIdx.x * 256 + threadIdx.x;
    if (i < n) outp[i] = rowtmp[i] + bsum[i >> 10];
    if (i == n) outp[n] = total;
}

// scatter packed (src | dstLow<<17) into bucket-partitioned part[]
__global__ void bucket_scatter(const int* __restrict__ eiS, const int* __restrict__ eiT,
                               const int* __restrict__ off, unsigned* __restrict__ part) {
    __shared__ int cur[NBUCK];
    int t = threadIdx.x;
    int side = blockIdx.x >= NBLK;
    int blk = blockIdx.x - side * NBLK;
    const int* ei = side ? eiT : eiS;
    if (t < NBUCK) cur[t] = off[side * (NBUCK * NBLK) + t * NBLK + blk];
    __syncthreads();
    int base4 = blk * (EPB / 4);
    #pragma unroll
    for (int k = 0; k < EPB / 1024; k++) {
        int i4 = base4 + k * 256 + t;
        if (i4 < NE / 4) {
            i32x4 s = __builtin_nontemporal_load(&((const i32x4*)ei)[i4]);
            i32x4 d = __builtin_nontemporal_load(&((const i32x4*)(ei + NE))[i4]);
            int p;
            p = atomicAdd(&cur[d.x >> 10], 1);
            __builtin_nontemporal_store((unsigned)s.x | ((unsigned)(d.x & 1023) << 17), &part[p]);
            p = atomicAdd(&cur[d.y >> 10], 1);
            __builtin_nontemporal_store((unsigned)s.y | ((unsigned)(d.y & 1023) << 17), &part[p]);
            p = atomicAdd(&cur[d.z >> 10], 1);
            __builtin_nontemporal_store((unsigned)s.z | ((unsigned)(d.z & 1023) << 17), &part[p]);
            p = atomicAdd(&cur[d.w >> 10], 1);
            __builtin_nontemporal_store((unsigned)s.w | ((unsigned)(d.w & 1023) << 17), &part[p]);
        }
    }
}

__global__ void bucket_csr(const unsigned* __restrict__ part, const int* __restrict__ off,
                           int* __restrict__ rowptrS, int* __restrict__ rowptrT,
                           int* __restrict__ csrsS, int* __restrict__ csrsT) {
    __shared__ int hist[1024];
    __shared__ int sh[1024];
    int t = threadIdx.x;           // 1024 threads
    int g = blockIdx.x;            // 0..2*NBUCK-1
    int side = g >= NBUCK;
    int bin = g - side * NBUCK;
    int start = off[g * NBLK];
    int end = off[(g + 1) * NBLK];
    hist[t] = 0;
    __syncthreads();
    for (int i = start + t; i < end; i += 1024) {
        unsigned u = __builtin_nontemporal_load(&part[i]);
        atomicAdd(&hist[u >> 17], 1);
    }
    __syncthreads();
    int own = hist[t];
    sh[t] = own;
    __syncthreads();
    for (int o = 1; o < 1024; o <<= 1) {
        int x = (t >= o) ? sh[t - o] : 0;
        __syncthreads();
        sh[t] += x;
        __syncthreads();
    }
    int excl = sh[t] - own;
    int node = bin * 1024 + t;
    int* rowptr = side ? rowptrT : rowptrS;
    if (node < NN) rowptr[node] = (start - side * NE) + excl;
    if (t == 0 && bin == NBUCK - 1) rowptr[NN] = NE;
    __syncthreads();
    hist[t] = start + excl;
    __syncthreads();
    int* csr = side ? csrsT : csrsS;
    int sub = side * NE;
    for (int i = start + t; i < end; i += 1024) {
        unsigned u = __builtin_nontemporal_load(&part[i]);
        int p = atomicAdd(&hist[u >> 17], 1);
        csr[p - sub] = (int)(u & 0x1FFFFu);
    }
}

// ---- batched L0 GEMM (K=8): WhS = x@WS, WhT = x@WT ----
__global__ void gemm2_k8(const float* __restrict__ x, const float* __restrict__ WS,
                         const float* __restrict__ WT, float* __restrict__ WhS,
                         float* __restrict__ WhT, int n) {
    const int nbh = (NN + 63) / 64;
    int side = blockIdx.x >= nbh;
    int blk = blockIdx.x - side * nbh;
    const float* W = side ? WT : WS;
    float* Wh = side ? WhT : WhS;
    __shared__ float Wl[8][HID];
    int t = threadIdx.x;
    for (int i = t; i < 8 * HID / 4; i += 256)
        ((float4*)Wl)[i] = ((const float4*)W)[i];
    __syncthreads();
    int node = blk * 64 + (t >> 2);
    int c0 = (t & 3) * 16;
    if (node >= n) return;
    float acc[16];
    #pragma unroll
    for (int j = 0; j < 16; j++) acc[j] = 0.f;
    const float* hr = x + (size_t)node * 8;
    #pragma unroll
    for (int k4 = 0; k4 < 2; k4++) {
        f32x4 hv = __builtin_nontemporal_load((const f32x4*)(hr + k4 * 4));
        #pragma unroll
        for (int j = 0; j < 16; j++)
            acc[j] += hv.x * Wl[k4*4+0][c0+j] + hv.y * Wl[k4*4+1][c0+j]
                    + hv.z * Wl[k4*4+2][c0+j] + hv.w * Wl[k4*4+3][c0+j];
    }
    float* o = Wh + (size_t)node * HID + c0;
    #pragma unroll
    for (int j = 0; j < 16; j += 4)
        *(float4*)(o + j) = make_float4(acc[j], acc[j+1], acc[j+2], acc[j+3]);
}

// ---- batched single-pass edge aggregation (both sides), fixed-shift exp ----
// lane layout: 8 groups of 8 lanes; group g handles edge i+g; lane holds 8 dims.
// R8 structure (node-strided, high occupancy) + nontemporal streams.
__global__ void edge_agg2(const float* __restrict__ WhS, const float* __restrict__ WhT,
                          const int* __restrict__ rowptrS, const int* __restrict__ rowptrT,
                          const int* __restrict__ csrsS, const int* __restrict__ csrsT,
                          const float* __restrict__ sum_a, int aiS, int aiT,
                          float* __restrict__ accS, float* __restrict__ accT,
                          float* __restrict__ bsumz, int n) {
    int side = blockIdx.x >= NBE;
    int blk = blockIdx.x - side * NBE;
    const float* Wh = side ? WhT : WhS;
    const int* rowptr = side ? rowptrT : rowptrS;
    const int* csrs = side ? csrsT : csrsS;
    float* acc = side ? accT : accS;
    float sa = sum_a[side ? aiT : aiS];
    int t = threadIdx.x;
    int w = t >> 6, lane = t & 63;
    int g = lane >> 3, l8 = lane & 7;
    float Zw = 0.f;                               // wave-level z accumulator
    for (int node = blk * 4 + w; node < n; node += NBE * 4) {
        const float* qp = Wh + (size_t)node * HID + l8 * 8;
        float4 q0 = *(const float4*)qp, q1 = *(const float4*)(qp + 4);
        int beg = rowptr[node], end = rowptr[node + 1];
        float z = 0.f;
        float4 a0 = make_float4(0,0,0,0), a1 = make_float4(0,0,0,0);
        for (int i = beg; i < end; i += 8) {
            int idx = i + g;
            bool act = idx < end;
            int s = __builtin_nontemporal_load(&csrs[act ? idx : beg]);
            const float* vp = Wh + (size_t)s * HID + l8 * 8;
            float4 v0 = *(const float4*)vp, v1 = *(const float4*)(vp + 4);
            float x = q0.x*v0.x + q0.y*v0.y + q0.z*v0.z + q0.w*v0.w
                    + q1.x*v1.x + q1.y*v1.y + q1.z*v1.z + q1.w*v1.w;
            x += __shfl_xor(x, 1); x += __shfl_xor(x, 2); x += __shfl_xor(x, 4);
            float e = x * sa;
            e = e > 0.f ? e : 0.2f * e;           // leaky_relu 0.2
            float wg = act ? __expf(e - ESHIFT) : 0.f;
            z += wg;
            a0.x += wg*v0.x; a0.y += wg*v0.y; a0.z += wg*v0.z; a0.w += wg*v0.w;
            a1.x += wg*v1.x; a1.y += wg*v1.y; a1.z += wg*v1.z; a1.w += wg*v1.w;
        }
        // merge 8 groups: pure-sum butterfly xor 8,16,32
        #pragma unroll
        for (int o = 8; o <= 32; o <<= 1) {
            z    += __shfl_xor(z, o);
            a0.x += __shfl_xor(a0.x, o); a0.y += __shfl_xor(a0.y, o);
            a0.z += __shfl_xor(a0.z, o); a0.w += __shfl_xor(a0.w, o);
            a1.x += __shfl_xor(a1.x, o); a1.y += __shfl_xor(a1.y, o);
            a1.z += __shfl_xor(a1.z, o); a1.w += __shfl_xor(a1.w, o);
        }
        if (g == 0) {
            float* ap = acc + (size_t)node * HID + l8 * 8;
            f32x4 w0 = { a0.x, a0.y, a0.z, a0.w };
            f32x4 w1 = { a1.x, a1.y, a1.z, a1.w };
            __builtin_nontemporal_store(w0, (f32x4*)ap);
            __builtin_nontemporal_store(w1, (f32x4*)(ap + 4));
        }
        Zw += z;   // all lanes hold the full node z after butterfly
    }
    __shared__ float shz[4];
    if (lane == 0) shz[w] = Zw;
    __syncthreads();
    if (t == 0) bsumz[blockIdx.x] = (shz[0] + shz[1]) + (shz[2] + shz[3]);
}

// in-block combine helper: invZ for one side from block sums
__device__ __forceinline__ float combine_invZ(const float* __restrict__ bsumz,
                                              int base, float* shred) {
    int t = threadIdx.x;
    float lz = 0.f;
    for (int i = t; i < NBE; i += 256) lz += bsumz[base + i];
    #pragma unroll
    for (int o = 32; o >= 1; o >>= 1) lz += __shfl_xor(lz, o);
    if ((t & 63) == 0) shred[t >> 6] = lz;
    __syncthreads();
    float Zt = (shred[0] + shred[1]) + (shred[2] + shred[3]);
    __syncthreads();
    return 1.f / Zt;
}

// ---- fused: combine + normalize + elu + LN(g0,b0) + GEMM(W1) -> Wh1, both sides ----
__global__ void normgemm2(const float* __restrict__ accS, const float* __restrict__ accT,
                          const float* __restrict__ bsumz,
                          const float* __restrict__ gS, const float* __restrict__ bS,
                          const float* __restrict__ gT, const float* __restrict__ bT,
                          const float* __restrict__ W1S, const float* __restrict__ W1T,
                          float* __restrict__ WhS, float* __restrict__ WhT, int n) {
    int side = blockIdx.x >= NBG;
    int blk = blockIdx.x - side * NBG;
    const float* acc = side ? accT : accS;
    const float* g = side ? gT : gS;
    const float* b = side ? bT : bS;
    const float* W1 = side ? W1T : W1S;
    float* Wh = side ? WhT : WhS;
    __shared__ float shred[4];
    float invZ = combine_invZ(bsumz, side * NBE, shred);
    __shared__ float Wl[64 * 64];
    int t = threadIdx.x;
    for (int i = t; i < 1024; i += 256)
        ((float4*)Wl)[i] = ((const float4*)W1)[i];
    __syncthreads();
    __shared__ float hrow[4][64];
    int w = t >> 6, lane = t & 63;
    float gl = g[lane], bl = b[lane];
    for (int node = blk * 4 + w; node < n; node += NBG * 4) {
        float v = __builtin_nontemporal_load(&acc[(size_t)node * HID + lane]) * invZ;
        v = v > 0.f ? v : expm1f(v);         // elu
        float s = v, s2 = v * v;
        #pragma unroll
        for (int o = 32; o >= 1; o >>= 1) {
            s += __shfl_xor(s, o);
            s2 += __shfl_xor(s2, o);
        }
        float mean = s * (1.f / 64.f);
        float var = s2 * (1.f / 64.f) - mean * mean;
        float hn = gl * (v - mean) * rsqrtf(var + 1e-5f) + bl;
        hrow[w][lane] = hn;
        float o2 = 0.f;
        #pragma unroll
        for (int k = 0; k < 64; k++) o2 += hrow[w][k] * Wl[k * 64 + lane];
        Wh[(size_t)node * HID + lane] = o2;
    }
}

// ---- fused: combine(both sides) + normalize + elu + LN(g1,b1) + final MLP ----
__global__ void normfinal(const float* __restrict__ accS, const float* __restrict__ accT,
                          const float* __restrict__ bsumz,
                          const float* __restrict__ gS, const float* __restrict__ bS,
                          const float* __restrict__ gT, const float* __restrict__ bT,
                          const float* __restrict__ cW1, const float* __restrict__ cb1,
                          const float* __restrict__ cW2, const float* __restrict__ cb2,
                          float* __restrict__ out, int n) {
    __shared__ float shred[4];
    float invZS = combine_invZ(bsumz, 0, shred);
    float invZT = combine_invZ(bsumz, NBE, shred);
    __shared__ float W1l[64 * 32];
    __shared__ float W2l[32], B1l[32];
    int t = threadIdx.x;
    for (int i = t; i < 512; i += 256)
        ((float4*)W1l)[i] = ((const float4*)cW1)[i];
    if (t < 32) { W2l[t] = cW2[t]; B1l[t] = cb1[t]; }
    __syncthreads();
    float c2 = cb2[0];
    __shared__ float hrow[4][64];
    int w = t >> 6, lane = t & 63;
    int j = lane & 31;
    float glS = gS[lane], blS = bS[lane], glT = gT[lane], blT = bT[lane];
    for (int node = blockIdx.x * 4 + w; node < n; node += NBF * 4) {
        // side S
        float vS = __builtin_nontemporal_load(&accS[(size_t)node * HID + lane]) * invZS;
        vS = vS > 0.f ? vS : expm1f(vS);
        float sA = vS, sB = vS * vS;
        #pragma unroll
        for (int o = 32; o >= 1; o >>= 1) { sA += __shfl_xor(sA, o); sB += __shfl_xor(sB, o); }
        float meanS = sA * (1.f / 64.f);
        float varS = sB * (1.f / 64.f) - meanS * meanS;
        float hS = glS * (vS - meanS) * rsqrtf(varS + 1e-5f) + blS;
        // side T
        float vT = __builtin_nontemporal_load(&accT[(size_t)node * HID + lane]) * invZT;
        vT = vT > 0.f ? vT : expm1f(vT);
        sA = vT; sB = vT * vT;
        #pragma unroll
        for (int o = 32; o >= 1; o >>= 1) { sA += __shfl_xor(sA, o); sB += __shfl_xor(sB, o); }
        float meanT = sA * (1.f / 64.f);
        float varT = sB * (1.f / 64.f) - meanT * meanT;
        float hT = glT * (vT - meanT) * rsqrtf(varT + 1e-5f) + blT;
        hrow[w][lane] = hS + hT;
        // MLP (lanes 0-31 and 32-63 compute the same j redundantly)
        float a = B1l[j];
        #pragma unroll
        for (int k = 0; k < 64; k++) a += hrow[w][k] * W1l[k * 32 + j];
        a = fmaxf(a, 0.f);
        float p = a * W2l[j];
        #pragma unroll
        for (int o = 16; o >= 1; o >>= 1) p += __shfl_xor(p, o, 32);
        if (lane == 0) out[node] = 1.f / (1.f + expf(-(p + c2)));
    }
}

extern "C" void kernel_launch(void* const* d_in, const int* in_sizes, int n_in,
                              void* d_out, int out_size, void* d_ws, size_t ws_size,
                              hipStream_t stream) {
    const float* x   = (const float*)d_in[0];
    const int*   ei  = (const int*)d_in[1];
    const int*   tei = (const int*)d_in[3];
    const float* sW0 = (const float*)d_in[4],  *sa0 = (const float*)d_in[5];
    const float* sg0 = (const float*)d_in[6],  *sb0 = (const float*)d_in[7];
    const float* sW1 = (const float*)d_in[8],  *sa1 = (const float*)d_in[9];
    const float* sg1 = (const float*)d_in[10], *sb1 = (const float*)d_in[11];
    const float* tW0 = (const float*)d_in[12], *ta0 = (const float*)d_in[13];
    const float* tg0 = (const float*)d_in[14], *tb0 = (const float*)d_in[15];
    const float* tW1 = (const float*)d_in[16], *ta1 = (const float*)d_in[17];
    const float* tg1 = (const float*)d_in[18], *tb1 = (const float*)d_in[19];
    const float* cW1 = (const float*)d_in[20], *cb1 = (const float*)d_in[21];
    const float* cW2 = (const float*)d_in[22], *cb2 = (const float*)d_in[23];
    float* out = (float*)d_out;

    float* ws = (float*)d_ws;
    size_t o = 0;
    float* hS  = ws + o; o += (size_t)NN * HID;   // acc S (aliased across layers)
    float* hT  = ws + o; o += (size_t)NN * HID;   // acc T
    float* WhS = ws + o; o += (size_t)NN * HID;
    float* WhT = ws + o; o += (size_t)NN * HID;
    float* bsumz = ws + o; o += 2 * NBE;
    float* sum_a = ws + o; o += 4;
    int* ip = (int*)(ws + o);
    int* rowptrS = ip; ip += NN + 1;
    int* rowptrT = ip; ip += NN + 1;
    int* csrsS   = ip; ip += NE;
    int* csrsT   = ip; ip += NE;

    // CSR-build scratch aliases WhS/WhT (only live before the layers)
    unsigned* part = (unsigned*)WhS;           // 3.2M packed entries = 12.8 MB
    int*  cnt    = (int*)WhT;                  // MATN+1
    int*  offm   = cnt + (MATN + 1);
    int*  rowtmp = offm + (MATN + 1);
    int*  bsum   = rowtmp + MATN;

    const int NSB = (MATN + 1023) / 1024;

    // ---- CSR build (both edge lists, bucket partition) ----
    bucket_hist<<<2 * NBLK, 256, 0, stream>>>(ei, tei, cnt);
    scanA<<<NSB, 256, 0, stream>>>(cnt, rowtmp, bsum, MATN);
    scanB<<<1, 256, 0, stream>>>(bsum, NSB, sa0, sa1, ta0, ta1, sum_a);
    scanC<<<(MATN + 256) / 256, 256, 0, stream>>>(rowtmp, bsum, offm, MATN, 2 * NE);
    bucket_scatter<<<2 * NBLK, 256, 0, stream>>>(ei, tei, offm, part);
    bucket_csr<<<2 * NBUCK, 1024, 0, stream>>>(part, offm, rowptrS, rowptrT, csrsS, csrsT);

    const int nbh = (NN + 63) / 64;

    // ---- layer 0 (batched S+T) ----
    gemm2_k8<<<2 * nbh, 256, 0, stream>>>(x, sW0, tW0, WhS, WhT, NN);
    edge_agg2<<<2 * NBE, 256, 0, stream>>>(WhS, WhT, rowptrS, rowptrT, csrsS, csrsT,
                                           sum_a, 0, 2, hS, hT, bsumz, NN);
    // L0 norm + L1 GEMM fused
    normgemm2<<<2 * NBG, 256, 0, stream>>>(hS, hT, bsumz,
                                           sg0, sb0, tg0, tb0, sW1, tW1, WhS, WhT, NN);
    // ---- layer 1 (batched S+T) ----
    edge_agg2<<<2 * NBE, 256, 0, stream>>>(WhS, WhT, rowptrS, rowptrT, csrsS, csrsT,
                                           sum_a, 1, 3, hS, hT, bsumz, NN);
    // L1 norm + final MLP fused
    normfinal<<<NBF, 256, 0, stream>>>(hS, hT, bsumz,
                                       sg1, sb1, tg1, tb1, cW1, cb1, cW2, cb2, out, NN);
}

// Round 12
// 458.629 us; speedup vs baseline: 1.2273x; 1.2273x over previous
//
#include <hip/hip_runtime.h>
#include <math.h>

#define NN 100000
#define NE 1600000
#define HID 64
#define NBE 2048                 // edge_agg blocks per side
#define NBG 2048                 // normgemm blocks per side
#define NBF 2048                 // normfinal blocks
#define EPB 2048                 // edges per bucket-build block
#define NBLK 782                 // ceil(NE/EPB)
#define NBUCK 98                 // ceil(NN/1024), bucket = dst>>10
#define MATN (2 * NBUCK * NBLK)  // count-matrix entries (both lists)
#define ESHIFT 30.0f             // fixed exponent shift: w = exp(e - ESHIFT)

// ================= CSR build: two-level bucket partition =================
__global__ void bucket_hist(const int* __restrict__ eiS, const int* __restrict__ eiT,
                            int* __restrict__ cnt) {
    __shared__ int hist[NBUCK];
    int t = threadIdx.x;
    int side = blockIdx.x >= NBLK;
    int blk = blockIdx.x - side * NBLK;
    const int4* dst4 = (const int4*)((side ? eiT : eiS) + NE);
    if (t < NBUCK) hist[t] = 0;
    __syncthreads();
    int base4 = blk * (EPB / 4);
    #pragma unroll
    for (int k = 0; k < EPB / 1024; k++) {       // 2 iters of 256 int4
        int i4 = base4 + k * 256 + t;
        if (i4 < NE / 4) {
            int4 d = dst4[i4];
            atomicAdd(&hist[d.x >> 10], 1);
            atomicAdd(&hist[d.y >> 10], 1);
            atomicAdd(&hist[d.z >> 10], 1);
            atomicAdd(&hist[d.w >> 10], 1);
        }
    }
    __syncthreads();
    if (t < NBUCK) cnt[side * (NBUCK * NBLK) + t * NBLK + blk] = hist[t];
}

__global__ void scanA(const int* __restrict__ deg, int* __restrict__ rowtmp,
                      int* __restrict__ bsum, int n) {
    __shared__ int sh[256];
    int t = threadIdx.x;
    int base = blockIdx.x * 1024 + t * 4;
    int a0 = (base + 0 < n) ? deg[base + 0] : 0;
    int a1 = (base + 1 < n) ? deg[base + 1] : 0;
    int a2 = (base + 2 < n) ? deg[base + 2] : 0;
    int a3 = (base + 3 < n) ? deg[base + 3] : 0;
    int s = a0 + a1 + a2 + a3;
    sh[t] = s;
    __syncthreads();
    for (int off = 1; off < 256; off <<= 1) {
        int x = (t >= off) ? sh[t - off] : 0;
        __syncthreads();
        sh[t] += x;
        __syncthreads();
    }
    int excl = sh[t] - s;
    if (t == 255) bsum[blockIdx.x] = sh[255];
    if (base + 0 < n) rowtmp[base + 0] = excl;
    if (base + 1 < n) rowtmp[base + 1] = excl + a0;
    if (base + 2 < n) rowtmp[base + 2] = excl + a0 + a1;
    if (base + 3 < n) rowtmp[base + 3] = excl + a0 + a1 + a2;
}

// scanB + prep4 fused (single-block kernel)
__global__ void scanB(int* __restrict__ bsum, int nb,
                      const float* __restrict__ a0, const float* __restrict__ a1,
                      const float* __restrict__ a2, const float* __restrict__ a3,
                      float* __restrict__ sum_a) {
    __shared__ int sh[256];
    int t = threadIdx.x;
    int v = (t < nb) ? bsum[t] : 0;
    sh[t] = v;
    __syncthreads();
    for (int off = 1; off < 256; off <<= 1) {
        int x = (t >= off) ? sh[t - off] : 0;
        __syncthreads();
        sh[t] += x;
        __syncthreads();
    }
    if (t < nb) bsum[t] = sh[t] - v; // exclusive
    // ---- prep4: sum of each attention vector (128 elems) ----
    int w = t >> 6, lane = t & 63;
    const float* a = (w == 0) ? a0 : (w == 1) ? a1 : (w == 2) ? a2 : a3;
    float av = a[lane] + a[lane + 64];
    #pragma unroll
    for (int o = 32; o >= 1; o >>= 1) av += __shfl_xor(av, o);
    if (lane == 0) sum_a[w] = av;
}

__global__ void scanC(const int* __restrict__ rowtmp, const int* __restrict__ bsum,
                      int* __restrict__ outp, int n, int total) {
    int i = blockIdx.x * 256 + threadIdx.x;
    if (i < n) outp[i] = rowtmp[i] + bsum[i >> 10];
    if (i == n) outp[n] = total;
}

// scatter packed (src | dstLow<<17) into bucket-partitioned part[] (normal stores!)
__global__ void bucket_scatter(const int* __restrict__ eiS, const int* __restrict__ eiT,
                               const int* __restrict__ off, unsigned* __restrict__ part) {
    __shared__ int cur[NBUCK];
    int t = threadIdx.x;
    int side = blockIdx.x >= NBLK;
    int blk = blockIdx.x - side * NBLK;
    const int* ei = side ? eiT : eiS;
    if (t < NBUCK) cur[t] = off[side * (NBUCK * NBLK) + t * NBLK + blk];
    __syncthreads();
    int base4 = blk * (EPB / 4);
    #pragma unroll
    for (int k = 0; k < EPB / 1024; k++) {
        int i4 = base4 + k * 256 + t;
        if (i4 < NE / 4) {
            int4 s = ((const int4*)ei)[i4];
            int4 d = ((const int4*)(ei + NE))[i4];
            int p;
            p = atomicAdd(&cur[d.x >> 10], 1);
            part[p] = (unsigned)s.x | ((unsigned)(d.x & 1023) << 17);
            p = atomicAdd(&cur[d.y >> 10], 1);
            part[p] = (unsigned)s.y | ((unsigned)(d.y & 1023) << 17);
            p = atomicAdd(&cur[d.z >> 10], 1);
            part[p] = (unsigned)s.z | ((unsigned)(d.z & 1023) << 17);
            p = atomicAdd(&cur[d.w >> 10], 1);
            part[p] = (unsigned)s.w | ((unsigned)(d.w & 1023) << 17);
        }
    }
}

__global__ void bucket_csr(const unsigned* __restrict__ part, const int* __restrict__ off,
                           int* __restrict__ rowptrS, int* __restrict__ rowptrT,
                           int* __restrict__ csrsS, int* __restrict__ csrsT) {
    __shared__ int hist[1024];
    __shared__ int sh[1024];
    int t = threadIdx.x;           // 1024 threads
    int g = blockIdx.x;            // 0..2*NBUCK-1
    int side = g >= NBUCK;
    int bin = g - side * NBUCK;
    int start = off[g * NBLK];
    int end = off[(g + 1) * NBLK];
    hist[t] = 0;
    __syncthreads();
    for (int i = start + t; i < end; i += 1024)
        atomicAdd(&hist[part[i] >> 17], 1);
    __syncthreads();
    int own = hist[t];
    sh[t] = own;
    __syncthreads();
    for (int o = 1; o < 1024; o <<= 1) {
        int x = (t >= o) ? sh[t - o] : 0;
        __syncthreads();
        sh[t] += x;
        __syncthreads();
    }
    int excl = sh[t] - own;
    int node = bin * 1024 + t;
    int* rowptr = side ? rowptrT : rowptrS;
    if (node < NN) rowptr[node] = (start - side * NE) + excl;
    if (t == 0 && bin == NBUCK - 1) rowptr[NN] = NE;
    __syncthreads();
    hist[t] = start + excl;
    __syncthreads();
    int* csr = side ? csrsT : csrsS;
    int sub = side * NE;
    for (int i = start + t; i < end; i += 1024) {
        unsigned u = part[i];
        int p = atomicAdd(&hist[u >> 17], 1);
        csr[p - sub] = (int)(u & 0x1FFFFu);
    }
}

// ---- batched L0 GEMM (K=8): WhS = x@WS, WhT = x@WT ----
__global__ void gemm2_k8(const float* __restrict__ x, const float* __restrict__ WS,
                         const float* __restrict__ WT, float* __restrict__ WhS,
                         float* __restrict__ WhT, int n) {
    const int nbh = (NN + 63) / 64;
    int side = blockIdx.x >= nbh;
    int blk = blockIdx.x - side * nbh;
    const float* W = side ? WT : WS;
    float* Wh = side ? WhT : WhS;
    __shared__ float Wl[8][HID];
    int t = threadIdx.x;
    for (int i = t; i < 8 * HID / 4; i += 256)
        ((float4*)Wl)[i] = ((const float4*)W)[i];
    __syncthreads();
    int node = blk * 64 + (t >> 2);
    int c0 = (t & 3) * 16;
    if (node >= n) return;
    float acc[16];
    #pragma unroll
    for (int j = 0; j < 16; j++) acc[j] = 0.f;
    const float* hr = x + (size_t)node * 8;
    #pragma unroll
    for (int k4 = 0; k4 < 2; k4++) {
        float4 hv = *(const float4*)(hr + k4 * 4);
        #pragma unroll
        for (int j = 0; j < 16; j++)
            acc[j] += hv.x * Wl[k4*4+0][c0+j] + hv.y * Wl[k4*4+1][c0+j]
                    + hv.z * Wl[k4*4+2][c0+j] + hv.w * Wl[k4*4+3][c0+j];
    }
    float* o = Wh + (size_t)node * HID + c0;
    #pragma unroll
    for (int j = 0; j < 16; j += 4)
        *(float4*)(o + j) = make_float4(acc[j], acc[j+1], acc[j+2], acc[j+3]);
}

// ---- batched single-pass edge aggregation (both sides), fixed-shift exp ----
// lane layout: 8 groups of 8 lanes; group g handles edge i+g; lane holds 8 dims.
// R8 structure: node-strided, 28 VGPR, ~80% occupancy. Plain loads (L2-friendly).
__global__ void edge_agg2(const float* __restrict__ WhS, const float* __restrict__ WhT,
                          const int* __restrict__ rowptrS, const int* __restrict__ rowptrT,
                          const int* __restrict__ csrsS, const int* __restrict__ csrsT,
                          const float* __restrict__ sum_a, int aiS, int aiT,
                          float* __restrict__ accS, float* __restrict__ accT,
                          float* __restrict__ bsumz, int n) {
    int side = blockIdx.x >= NBE;
    int blk = blockIdx.x - side * NBE;
    const float* Wh = side ? WhT : WhS;
    const int* rowptr = side ? rowptrT : rowptrS;
    const int* csrs = side ? csrsT : csrsS;
    float* acc = side ? accT : accS;
    float sa = sum_a[side ? aiT : aiS];
    int t = threadIdx.x;
    int w = t >> 6, lane = t & 63;
    int g = lane >> 3, l8 = lane & 7;
    float Zw = 0.f;                               // wave-level z accumulator
    for (int node = blk * 4 + w; node < n; node += NBE * 4) {
        const float* qp = Wh + (size_t)node * HID + l8 * 8;
        float4 q0 = *(const float4*)qp, q1 = *(const float4*)(qp + 4);
        int beg = rowptr[node], end = rowptr[node + 1];
        float z = 0.f;
        float4 a0 = make_float4(0,0,0,0), a1 = make_float4(0,0,0,0);
        for (int i = beg; i < end; i += 8) {
            int idx = i + g;
            bool act = idx < end;
            int s = csrs[act ? idx : beg];
            const float* vp = Wh + (size_t)s * HID + l8 * 8;
            float4 v0 = *(const float4*)vp, v1 = *(const float4*)(vp + 4);
            float x = q0.x*v0.x + q0.y*v0.y + q0.z*v0.z + q0.w*v0.w
                    + q1.x*v1.x + q1.y*v1.y + q1.z*v1.z + q1.w*v1.w;
            x += __shfl_xor(x, 1); x += __shfl_xor(x, 2); x += __shfl_xor(x, 4);
            float e = x * sa;
            e = e > 0.f ? e : 0.2f * e;           // leaky_relu 0.2
            float wg = act ? __expf(e - ESHIFT) : 0.f;
            z += wg;
            a0.x += wg*v0.x; a0.y += wg*v0.y; a0.z += wg*v0.z; a0.w += wg*v0.w;
            a1.x += wg*v1.x; a1.y += wg*v1.y; a1.z += wg*v1.z; a1.w += wg*v1.w;
        }
        // merge 8 groups: pure-sum butterfly xor 8,16,32
        #pragma unroll
        for (int o = 8; o <= 32; o <<= 1) {
            z    += __shfl_xor(z, o);
            a0.x += __shfl_xor(a0.x, o); a0.y += __shfl_xor(a0.y, o);
            a0.z += __shfl_xor(a0.z, o); a0.w += __shfl_xor(a0.w, o);
            a1.x += __shfl_xor(a1.x, o); a1.y += __shfl_xor(a1.y, o);
            a1.z += __shfl_xor(a1.z, o); a1.w += __shfl_xor(a1.w, o);
        }
        if (g == 0) {
            float* ap = acc + (size_t)node * HID + l8 * 8;
            *(float4*)ap = a0; *(float4*)(ap + 4) = a1;
        }
        Zw += z;   // all lanes hold the full node z after butterfly
    }
    __shared__ float shz[4];
    if (lane == 0) shz[w] = Zw;
    __syncthreads();
    if (t == 0) bsumz[blockIdx.x] = (shz[0] + shz[1]) + (shz[2] + shz[3]);
}

// in-block combine helper: invZ for one side from block sums
__device__ __forceinline__ float combine_invZ(const float* __restrict__ bsumz,
                                              int base, float* shred) {
    int t = threadIdx.x;
    float lz = 0.f;
    for (int i = t; i < NBE; i += 256) lz += bsumz[base + i];
    #pragma unroll
    for (int o = 32; o >= 1; o >>= 1) lz += __shfl_xor(lz, o);
    if ((t & 63) == 0) shred[t >> 6] = lz;
    __syncthreads();
    float Zt = (shred[0] + shred[1]) + (shred[2] + shred[3]);
    __syncthreads();
    return 1.f / Zt;
}

// ---- fused: combine + normalize + elu + LN(g0,b0) + GEMM(W1) -> Wh1, both sides ----
__global__ void normgemm2(const float* __restrict__ accS, const float* __restrict__ accT,
                          const float* __restrict__ bsumz,
                          const float* __restrict__ gS, const float* __restrict__ bS,
                          const float* __restrict__ gT, const float* __restrict__ bT,
                          const float* __restrict__ W1S, const float* __restrict__ W1T,
                          float* __restrict__ WhS, float* __restrict__ WhT, int n) {
    int side = blockIdx.x >= NBG;
    int blk = blockIdx.x - side * NBG;
    const float* acc = side ? accT : accS;
    const float* g = side ? gT : gS;
    const float* b = side ? bT : bS;
    const float* W1 = side ? W1T : W1S;
    float* Wh = side ? WhT : WhS;
    __shared__ float shred[4];
    float invZ = combine_invZ(bsumz, side * NBE, shred);
    __shared__ float Wl[64 * 64];
    int t = threadIdx.x;
    for (int i = t; i < 1024; i += 256)
        ((float4*)Wl)[i] = ((const float4*)W1)[i];
    __syncthreads();
    __shared__ float hrow[4][64];
    int w = t >> 6, lane = t & 63;
    float gl = g[lane], bl = b[lane];
    for (int node = blk * 4 + w; node < n; node += NBG * 4) {
        float v = acc[(size_t)node * HID + lane] * invZ;
        v = v > 0.f ? v : expm1f(v);         // elu
        float s = v, s2 = v * v;
        #pragma unroll
        for (int o = 32; o >= 1; o >>= 1) {
            s += __shfl_xor(s, o);
            s2 += __shfl_xor(s2, o);
        }
        float mean = s * (1.f / 64.f);
        float var = s2 * (1.f / 64.f) - mean * mean;
        float hn = gl * (v - mean) * rsqrtf(var + 1e-5f) + bl;
        hrow[w][lane] = hn;
        float o2 = 0.f;
        #pragma unroll
        for (int k = 0; k < 64; k++) o2 += hrow[w][k] * Wl[k * 64 + lane];
        Wh[(size_t)node * HID + lane] = o2;
    }
}

// ---- fused: combine(both sides) + normalize + elu + LN(g1,b1) + final MLP ----
__global__ void normfinal(const float* __restrict__ accS, const float* __restrict__ accT,
                          const float* __restrict__ bsumz,
                          const float* __restrict__ gS, const float* __restrict__ bS,
                          const float* __restrict__ gT, const float* __restrict__ bT,
                          const float* __restrict__ cW1, const float* __restrict__ cb1,
                          const float* __restrict__ cW2, const float* __restrict__ cb2,
                          float* __restrict__ out, int n) {
    __shared__ float shred[4];
    float invZS = combine_invZ(bsumz, 0, shred);
    float invZT = combine_invZ(bsumz, NBE, shred);
    __shared__ float W1l[64 * 32];
    __shared__ float W2l[32], B1l[32];
    int t = threadIdx.x;
    for (int i = t; i < 512; i += 256)
        ((float4*)W1l)[i] = ((const float4*)cW1)[i];
    if (t < 32) { W2l[t] = cW2[t]; B1l[t] = cb1[t]; }
    __syncthreads();
    float c2 = cb2[0];
    __shared__ float hrow[4][64];
    int w = t >> 6, lane = t & 63;
    int j = lane & 31;
    float glS = gS[lane], blS = bS[lane], glT = gT[lane], blT = bT[lane];
    for (int node = blockIdx.x * 4 + w; node < n; node += NBF * 4) {
        // side S
        float vS = accS[(size_t)node * HID + lane] * invZS;
        vS = vS > 0.f ? vS : expm1f(vS);
        float sA = vS, sB = vS * vS;
        #pragma unroll
        for (int o = 32; o >= 1; o >>= 1) { sA += __shfl_xor(sA, o); sB += __shfl_xor(sB, o); }
        float meanS = sA * (1.f / 64.f);
        float varS = sB * (1.f / 64.f) - meanS * meanS;
        float hS = glS * (vS - meanS) * rsqrtf(varS + 1e-5f) + blS;
        // side T
        float vT = accT[(size_t)node * HID + lane] * invZT;
        vT = vT > 0.f ? vT : expm1f(vT);
        sA = vT; sB = vT * vT;
        #pragma unroll
        for (int o = 32; o >= 1; o >>= 1) { sA += __shfl_xor(sA, o); sB += __shfl_xor(sB, o); }
        float meanT = sA * (1.f / 64.f);
        float varT = sB * (1.f / 64.f) - meanT * meanT;
        float hT = glT * (vT - meanT) * rsqrtf(varT + 1e-5f) + blT;
        hrow[w][lane] = hS + hT;
        // MLP (lanes 0-31 and 32-63 compute the same j redundantly)
        float a = B1l[j];
        #pragma unroll
        for (int k = 0; k < 64; k++) a += hrow[w][k] * W1l[k * 32 + j];
        a = fmaxf(a, 0.f);
        float p = a * W2l[j];
        #pragma unroll
        for (int o = 16; o >= 1; o >>= 1) p += __shfl_xor(p, o, 32);
        if (lane == 0) out[node] = 1.f / (1.f + expf(-(p + c2)));
    }
}

extern "C" void kernel_launch(void* const* d_in, const int* in_sizes, int n_in,
                              void* d_out, int out_size, void* d_ws, size_t ws_size,
                              hipStream_t stream) {
    const float* x   = (const float*)d_in[0];
    const int*   ei  = (const int*)d_in[1];
    const int*   tei = (const int*)d_in[3];
    const float* sW0 = (const float*)d_in[4],  *sa0 = (const float*)d_in[5];
    const float* sg0 = (const float*)d_in[6],  *sb0 = (const float*)d_in[7];
    const float* sW1 = (const float*)d_in[8],  *sa1 = (const float*)d_in[9];
    const float* sg1 = (const float*)d_in[10], *sb1 = (const float*)d_in[11];
    const float* tW0 = (const float*)d_in[12], *ta0 = (const float*)d_in[13];
    const float* tg0 = (const float*)d_in[14], *tb0 = (const float*)d_in[15];
    const float* tW1 = (const float*)d_in[16], *ta1 = (const float*)d_in[17];
    const float* tg1 = (const float*)d_in[18], *tb1 = (const float*)d_in[19];
    const float* cW1 = (const float*)d_in[20], *cb1 = (const float*)d_in[21];
    const float* cW2 = (const float*)d_in[22], *cb2 = (const float*)d_in[23];
    float* out = (float*)d_out;

    float* ws = (float*)d_ws;
    size_t o = 0;
    float* hS  = ws + o; o += (size_t)NN * HID;   // acc S (aliased across layers)
    float* hT  = ws + o; o += (size_t)NN * HID;   // acc T
    float* WhS = ws + o; o += (size_t)NN * HID;
    float* WhT = ws + o; o += (size_t)NN * HID;
    float* bsumz = ws + o; o += 2 * NBE;
    float* sum_a = ws + o; o += 4;
    int* ip = (int*)(ws + o);
    int* rowptrS = ip; ip += NN + 1;
    int* rowptrT = ip; ip += NN + 1;
    int* csrsS   = ip; ip += NE;
    int* csrsT   = ip; ip += NE;

    // CSR-build scratch aliases WhS/WhT (only live before the layers)
    unsigned* part = (unsigned*)WhS;           // 3.2M packed entries = 12.8 MB
    int*  cnt    = (int*)WhT;                  // MATN+1
    int*  offm   = cnt + (MATN + 1);
    int*  rowtmp = offm + (MATN + 1);
    int*  bsum   = rowtmp + MATN;

    const int NSB = (MATN + 1023) / 1024;

    // ---- CSR build (both edge lists, bucket partition) ----
    bucket_hist<<<2 * NBLK, 256, 0, stream>>>(ei, tei, cnt);
    scanA<<<NSB, 256, 0, stream>>>(cnt, rowtmp, bsum, MATN);
    scanB<<<1, 256, 0, stream>>>(bsum, NSB, sa0, sa1, ta0, ta1, sum_a);
    scanC<<<(MATN + 256) / 256, 256, 0, stream>>>(rowtmp, bsum, offm, MATN, 2 * NE);
    bucket_scatter<<<2 * NBLK, 256, 0, stream>>>(ei, tei, offm, part);
    bucket_csr<<<2 * NBUCK, 1024, 0, stream>>>(part, offm, rowptrS, rowptrT, csrsS, csrsT);

    const int nbh = (NN + 63) / 64;

    // ---- layer 0 (batched S+T) ----
    gemm2_k8<<<2 * nbh, 256, 0, stream>>>(x, sW0, tW0, WhS, WhT, NN);
    edge_agg2<<<2 * NBE, 256, 0, stream>>>(WhS, WhT, rowptrS, rowptrT, csrsS, csrsT,
                                           sum_a, 0, 2, hS, hT, bsumz, NN);
    // L0 norm + L1 GEMM fused
    normgemm2<<<2 * NBG, 256, 0, stream>>>(hS, hT, bsumz,
                                           sg0, sb0, tg0, tb0, sW1, tW1, WhS, WhT, NN);
    // ---- layer 1 (batched S+T) ----
    edge_agg2<<<2 * NBE, 256, 0, stream>>>(WhS, WhT, rowptrS, rowptrT, csrsS, csrsT,
                                           sum_a, 1, 3, hS, hT, bsumz, NN);
    // L1 norm + final MLP fused
    normfinal<<<NBF, 256, 0, stream>>>(hS, hT, bsumz,
                                       sg1, sb1, tg1, tb1, cW1, cb1, cW2, cb2, out, NN);
}

// Round 13
// 455.512 us; speedup vs baseline: 1.2357x; 1.0068x over previous
//
#include <hip/hip_runtime.h>
#include <math.h>

#define NN 100000
#define NE 1600000
#define HID 64
#define NBE 2048                 // edge_agg blocks per side
#define NBG 2048                 // normgemm blocks per side
#define NBF 2048                 // normfinal blocks
#define EPB 4096                 // edges per bucket-build block
#define NBLK 391                 // ceil(NE/EPB)
#define NBUCK 98                 // ceil(NN/1024), bucket = dst>>10
#define MATN (2 * NBUCK * NBLK)  // count-matrix entries (both lists)
#define ESHIFT 30.0f             // fixed exponent shift: w = exp(e - ESHIFT)

// ================= CSR build: two-level bucket partition =================
__global__ void bucket_hist(const int* __restrict__ eiS, const int* __restrict__ eiT,
                            int* __restrict__ cnt) {
    __shared__ int hist[NBUCK];
    int t = threadIdx.x;
    int side = blockIdx.x >= NBLK;
    int blk = blockIdx.x - side * NBLK;
    const int4* dst4 = (const int4*)((side ? eiT : eiS) + NE);
    if (t < NBUCK) hist[t] = 0;
    __syncthreads();
    int base4 = blk * (EPB / 4);
    #pragma unroll
    for (int k = 0; k < EPB / 1024; k++) {       // 4 iters of 256 int4
        int i4 = base4 + k * 256 + t;
        if (i4 < NE / 4) {
            int4 d = dst4[i4];
            atomicAdd(&hist[d.x >> 10], 1);
            atomicAdd(&hist[d.y >> 10], 1);
            atomicAdd(&hist[d.z >> 10], 1);
            atomicAdd(&hist[d.w >> 10], 1);
        }
    }
    __syncthreads();
    if (t < NBUCK) cnt[side * (NBUCK * NBLK) + t * NBLK + blk] = hist[t];
}

__global__ void scanA(const int* __restrict__ deg, int* __restrict__ rowtmp,
                      int* __restrict__ bsum, int n) {
    __shared__ int sh[256];
    int t = threadIdx.x;
    int base = blockIdx.x * 1024 + t * 4;
    int a0 = (base + 0 < n) ? deg[base + 0] : 0;
    int a1 = (base + 1 < n) ? deg[base + 1] : 0;
    int a2 = (base + 2 < n) ? deg[base + 2] : 0;
    int a3 = (base + 3 < n) ? deg[base + 3] : 0;
    int s = a0 + a1 + a2 + a3;
    sh[t] = s;
    __syncthreads();
    for (int off = 1; off < 256; off <<= 1) {
        int x = (t >= off) ? sh[t - off] : 0;
        __syncthreads();
        sh[t] += x;
        __syncthreads();
    }
    int excl = sh[t] - s;
    if (t == 255) bsum[blockIdx.x] = sh[255];
    if (base + 0 < n) rowtmp[base + 0] = excl;
    if (base + 1 < n) rowtmp[base + 1] = excl + a0;
    if (base + 2 < n) rowtmp[base + 2] = excl + a0 + a1;
    if (base + 3 < n) rowtmp[base + 3] = excl + a0 + a1 + a2;
}

// scanB + prep4 fused (single-block kernel)
__global__ void scanB(int* __restrict__ bsum, int nb,
                      const float* __restrict__ a0, const float* __restrict__ a1,
                      const float* __restrict__ a2, const float* __restrict__ a3,
                      float* __restrict__ sum_a) {
    __shared__ int sh[256];
    int t = threadIdx.x;
    int v = (t < nb) ? bsum[t] : 0;
    sh[t] = v;
    __syncthreads();
    for (int off = 1; off < 256; off <<= 1) {
        int x = (t >= off) ? sh[t - off] : 0;
        __syncthreads();
        sh[t] += x;
        __syncthreads();
    }
    if (t < nb) bsum[t] = sh[t] - v; // exclusive
    // ---- prep4: sum of each attention vector (128 elems) ----
    int w = t >> 6, lane = t & 63;
    const float* a = (w == 0) ? a0 : (w == 1) ? a1 : (w == 2) ? a2 : a3;
    float av = a[lane] + a[lane + 64];
    #pragma unroll
    for (int o = 32; o >= 1; o >>= 1) av += __shfl_xor(av, o);
    if (lane == 0) sum_a[w] = av;
}

// offm(i) computed inline: rowtmp[i] + bsum[i>>10]
__device__ __forceinline__ int offm_at(const int* __restrict__ rowtmp,
                                       const int* __restrict__ bsum, int i) {
    return rowtmp[i] + bsum[i >> 10];
}

// scatter packed (src | dstLow<<17) into bucket-partitioned part[]
__global__ void bucket_scatter(const int* __restrict__ eiS, const int* __restrict__ eiT,
                               const int* __restrict__ rowtmp, const int* __restrict__ bsum,
                               unsigned* __restrict__ part) {
    __shared__ int cur[NBUCK];
    int t = threadIdx.x;
    int side = blockIdx.x >= NBLK;
    int blk = blockIdx.x - side * NBLK;
    const int* ei = side ? eiT : eiS;
    if (t < NBUCK) cur[t] = offm_at(rowtmp, bsum, side * (NBUCK * NBLK) + t * NBLK + blk);
    __syncthreads();
    int base4 = blk * (EPB / 4);
    #pragma unroll
    for (int k = 0; k < EPB / 1024; k++) {
        int i4 = base4 + k * 256 + t;
        if (i4 < NE / 4) {
            int4 s = ((const int4*)ei)[i4];
            int4 d = ((const int4*)(ei + NE))[i4];
            int p;
            p = atomicAdd(&cur[d.x >> 10], 1);
            part[p] = (unsigned)s.x | ((unsigned)(d.x & 1023) << 17);
            p = atomicAdd(&cur[d.y >> 10], 1);
            part[p] = (unsigned)s.y | ((unsigned)(d.y & 1023) << 17);
            p = atomicAdd(&cur[d.z >> 10], 1);
            part[p] = (unsigned)s.z | ((unsigned)(d.z & 1023) << 17);
            p = atomicAdd(&cur[d.w >> 10], 1);
            part[p] = (unsigned)s.w | ((unsigned)(d.w & 1023) << 17);
        }
    }
}

__global__ void bucket_csr(const unsigned* __restrict__ part,
                           const int* __restrict__ rowtmp, const int* __restrict__ bsum,
                           int* __restrict__ rowptrS, int* __restrict__ rowptrT,
                           int* __restrict__ csrsS, int* __restrict__ csrsT) {
    __shared__ int hist[1024];
    __shared__ int wsum[16];
    int t = threadIdx.x;           // 1024 threads
    int g = blockIdx.x;            // 0..2*NBUCK-1
    int side = g >= NBUCK;
    int bin = g - side * NBUCK;
    int start = offm_at(rowtmp, bsum, g * NBLK);
    int end = (g == 2 * NBUCK - 1) ? 2 * NE : offm_at(rowtmp, bsum, (g + 1) * NBLK);
    hist[t] = 0;
    __syncthreads();
    for (int i = start + t; i < end; i += 1024)
        atomicAdd(&hist[part[i] >> 17], 1);
    __syncthreads();
    int own = hist[t];
    // barrier-light scan: wave shfl inclusive scan + wave-sum combine
    int wv = t >> 6, lane = t & 63;
    int incl = own;
    #pragma unroll
    for (int o = 1; o < 64; o <<= 1) {
        int y = __shfl_up(incl, o);
        if (lane >= o) incl += y;
    }
    if (lane == 63) wsum[wv] = incl;
    __syncthreads();
    int wpre = 0;
    for (int k = 0; k < wv; k++) wpre += wsum[k];
    int excl = wpre + incl - own;
    int node = bin * 1024 + t;
    int* rowptr = side ? rowptrT : rowptrS;
    if (node < NN) rowptr[node] = (start - side * NE) + excl;
    if (t == 0 && bin == NBUCK - 1) rowptr[NN] = NE;
    __syncthreads();
    hist[t] = start + excl;        // reuse as cursor (part-space)
    __syncthreads();
    int* csr = side ? csrsT : csrsS;
    int sub = side * NE;
    for (int i = start + t; i < end; i += 1024) {
        unsigned u = part[i];
        int p = atomicAdd(&hist[u >> 17], 1);
        csr[p - sub] = (int)(u & 0x1FFFFu);
    }
}

// ---- batched L0 GEMM (K=8): WhS = x@WS, WhT = x@WT ----
__global__ void gemm2_k8(const float* __restrict__ x, const float* __restrict__ WS,
                         const float* __restrict__ WT, float* __restrict__ WhS,
                         float* __restrict__ WhT, int n) {
    const int nbh = (NN + 63) / 64;
    int side = blockIdx.x >= nbh;
    int blk = blockIdx.x - side * nbh;
    const float* W = side ? WT : WS;
    float* Wh = side ? WhT : WhS;
    __shared__ float Wl[8][HID];
    int t = threadIdx.x;
    for (int i = t; i < 8 * HID / 4; i += 256)
        ((float4*)Wl)[i] = ((const float4*)W)[i];
    __syncthreads();
    int node = blk * 64 + (t >> 2);
    int c0 = (t & 3) * 16;
    if (node >= n) return;
    float acc[16];
    #pragma unroll
    for (int j = 0; j < 16; j++) acc[j] = 0.f;
    const float* hr = x + (size_t)node * 8;
    #pragma unroll
    for (int k4 = 0; k4 < 2; k4++) {
        float4 hv = *(const float4*)(hr + k4 * 4);
        #pragma unroll
        for (int j = 0; j < 16; j++)
            acc[j] += hv.x * Wl[k4*4+0][c0+j] + hv.y * Wl[k4*4+1][c0+j]
                    + hv.z * Wl[k4*4+2][c0+j] + hv.w * Wl[k4*4+3][c0+j];
    }
    float* o = Wh + (size_t)node * HID + c0;
    #pragma unroll
    for (int j = 0; j < 16; j += 4)
        *(float4*)(o + j) = make_float4(acc[j], acc[j+1], acc[j+2], acc[j+3]);
}

// ---- batched single-pass edge aggregation (both sides), fixed-shift exp ----
// lane layout: 8 groups of 8 lanes; group g handles edge i+g; lane holds 8 dims.
// R8/R12 structure: node-strided, 28 VGPR, ~80% occupancy, plain loads.
__global__ void edge_agg2(const float* __restrict__ WhS, const float* __restrict__ WhT,
                          const int* __restrict__ rowptrS, const int* __restrict__ rowptrT,
                          const int* __restrict__ csrsS, const int* __restrict__ csrsT,
                          const float* __restrict__ sum_a, int aiS, int aiT,
                          float* __restrict__ accS, float* __restrict__ accT,
                          float* __restrict__ bsumz, int n) {
    int side = blockIdx.x >= NBE;
    int blk = blockIdx.x - side * NBE;
    const float* Wh = side ? WhT : WhS;
    const int* rowptr = side ? rowptrT : rowptrS;
    const int* csrs = side ? csrsT : csrsS;
    float* acc = side ? accT : accS;
    float sa = sum_a[side ? aiT : aiS];
    int t = threadIdx.x;
    int w = t >> 6, lane = t & 63;
    int g = lane >> 3, l8 = lane & 7;
    float Zw = 0.f;                               // wave-level z accumulator
    for (int node = blk * 4 + w; node < n; node += NBE * 4) {
        const float* qp = Wh + (size_t)node * HID + l8 * 8;
        float4 q0 = *(const float4*)qp, q1 = *(const float4*)(qp + 4);
        int beg = rowptr[node], end = rowptr[node + 1];
        float z = 0.f;
        float4 a0 = make_float4(0,0,0,0), a1 = make_float4(0,0,0,0);
        for (int i = beg; i < end; i += 8) {
            int idx = i + g;
            bool act = idx < end;
            int s = csrs[act ? idx : beg];
            const float* vp = Wh + (size_t)s * HID + l8 * 8;
            float4 v0 = *(const float4*)vp, v1 = *(const float4*)(vp + 4);
            float x = q0.x*v0.x + q0.y*v0.y + q0.z*v0.z + q0.w*v0.w
                    + q1.x*v1.x + q1.y*v1.y + q1.z*v1.z + q1.w*v1.w;
            x += __shfl_xor(x, 1); x += __shfl_xor(x, 2); x += __shfl_xor(x, 4);
            float e = x * sa;
            e = e > 0.f ? e : 0.2f * e;           // leaky_relu 0.2
            float wg = act ? __expf(e - ESHIFT) : 0.f;
            z += wg;
            a0.x += wg*v0.x; a0.y += wg*v0.y; a0.z += wg*v0.z; a0.w += wg*v0.w;
            a1.x += wg*v1.x; a1.y += wg*v1.y; a1.z += wg*v1.z; a1.w += wg*v1.w;
        }
        // merge 8 groups: pure-sum butterfly xor 8,16,32
        #pragma unroll
        for (int o = 8; o <= 32; o <<= 1) {
            z    += __shfl_xor(z, o);
            a0.x += __shfl_xor(a0.x, o); a0.y += __shfl_xor(a0.y, o);
            a0.z += __shfl_xor(a0.z, o); a0.w += __shfl_xor(a0.w, o);
            a1.x += __shfl_xor(a1.x, o); a1.y += __shfl_xor(a1.y, o);
            a1.z += __shfl_xor(a1.z, o); a1.w += __shfl_xor(a1.w, o);
        }
        if (g == 0) {
            float* ap = acc + (size_t)node * HID + l8 * 8;
            *(float4*)ap = a0; *(float4*)(ap + 4) = a1;
        }
        Zw += z;   // all lanes hold the full node z after butterfly
    }
    __shared__ float shz[4];
    if (lane == 0) shz[w] = Zw;
    __syncthreads();
    if (t == 0) bsumz[blockIdx.x] = (shz[0] + shz[1]) + (shz[2] + shz[3]);
}

// in-block combine helper: invZ for one side from block sums
__device__ __forceinline__ float combine_invZ(const float* __restrict__ bsumz,
                                              int base, float* shred) {
    int t = threadIdx.x;
    float lz = 0.f;
    for (int i = t; i < NBE; i += 256) lz += bsumz[base + i];
    #pragma unroll
    for (int o = 32; o >= 1; o >>= 1) lz += __shfl_xor(lz, o);
    if ((t & 63) == 0) shred[t >> 6] = lz;
    __syncthreads();
    float Zt = (shred[0] + shred[1]) + (shred[2] + shred[3]);
    __syncthreads();
    return 1.f / Zt;
}

// ---- fused: combine + normalize + elu + LN(g0,b0) + GEMM(W1) -> Wh1, both sides ----
__global__ void normgemm2(const float* __restrict__ accS, const float* __restrict__ accT,
                          const float* __restrict__ bsumz,
                          const float* __restrict__ gS, const float* __restrict__ bS,
                          const float* __restrict__ gT, const float* __restrict__ bT,
                          const float* __restrict__ W1S, const float* __restrict__ W1T,
                          float* __restrict__ WhS, float* __restrict__ WhT, int n) {
    int side = blockIdx.x >= NBG;
    int blk = blockIdx.x - side * NBG;
    const float* acc = side ? accT : accS;
    const float* g = side ? gT : gS;
    const float* b = side ? bT : bS;
    const float* W1 = side ? W1T : W1S;
    float* Wh = side ? WhT : WhS;
    __shared__ float shred[4];
    float invZ = combine_invZ(bsumz, side * NBE, shred);
    __shared__ float Wl[64 * 64];
    int t = threadIdx.x;
    for (int i = t; i < 1024; i += 256)
        ((float4*)Wl)[i] = ((const float4*)W1)[i];
    __syncthreads();
    __shared__ float hrow[4][64];
    int w = t >> 6, lane = t & 63;
    float gl = g[lane], bl = b[lane];
    for (int node = blk * 4 + w; node < n; node += NBG * 4) {
        float v = acc[(size_t)node * HID + lane] * invZ;
        v = v > 0.f ? v : expm1f(v);         // elu
        float s = v, s2 = v * v;
        #pragma unroll
        for (int o = 32; o >= 1; o >>= 1) {
            s += __shfl_xor(s, o);
            s2 += __shfl_xor(s2, o);
        }
        float mean = s * (1.f / 64.f);
        float var = s2 * (1.f / 64.f) - mean * mean;
        float hn = gl * (v - mean) * rsqrtf(var + 1e-5f) + bl;
        hrow[w][lane] = hn;
        float o2 = 0.f;
        #pragma unroll
        for (int k = 0; k < 64; k++) o2 += hrow[w][k] * Wl[k * 64 + lane];
        Wh[(size_t)node * HID + lane] = o2;
    }
}

// ---- fused: combine(both sides) + normalize + elu + LN(g1,b1) + final MLP ----
__global__ void normfinal(const float* __restrict__ accS, const float* __restrict__ accT,
                          const float* __restrict__ bsumz,
                          const float* __restrict__ gS, const float* __restrict__ bS,
                          const float* __restrict__ gT, const float* __restrict__ bT,
                          const float* __restrict__ cW1, const float* __restrict__ cb1,
                          const float* __restrict__ cW2, const float* __restrict__ cb2,
                          float* __restrict__ out, int n) {
    __shared__ float shred[4];
    float invZS = combine_invZ(bsumz, 0, shred);
    float invZT = combine_invZ(bsumz, NBE, shred);
    __shared__ float W1l[64 * 32];
    __shared__ float W2l[32], B1l[32];
    int t = threadIdx.x;
    for (int i = t; i < 512; i += 256)
        ((float4*)W1l)[i] = ((const float4*)cW1)[i];
    if (t < 32) { W2l[t] = cW2[t]; B1l[t] = cb1[t]; }
    __syncthreads();
    float c2 = cb2[0];
    __shared__ float hrow[4][64];
    int w = t >> 6, lane = t & 63;
    int j = lane & 31;
    float glS = gS[lane], blS = bS[lane], glT = gT[lane], blT = bT[lane];
    for (int node = blockIdx.x * 4 + w; node < n; node += NBF * 4) {
        // side S
        float vS = accS[(size_t)node * HID + lane] * invZS;
        vS = vS > 0.f ? vS : expm1f(vS);
        float sA = vS, sB = vS * vS;
        #pragma unroll
        for (int o = 32; o >= 1; o >>= 1) { sA += __shfl_xor(sA, o); sB += __shfl_xor(sB, o); }
        float meanS = sA * (1.f / 64.f);
        float varS = sB * (1.f / 64.f) - meanS * meanS;
        float hS = glS * (vS - meanS) * rsqrtf(varS + 1e-5f) + blS;
        // side T
        float vT = accT[(size_t)node * HID + lane] * invZT;
        vT = vT > 0.f ? vT : expm1f(vT);
        sA = vT; sB = vT * vT;
        #pragma unroll
        for (int o = 32; o >= 1; o >>= 1) { sA += __shfl_xor(sA, o); sB += __shfl_xor(sB, o); }
        float meanT = sA * (1.f / 64.f);
        float varT = sB * (1.f / 64.f) - meanT * meanT;
        float hT = glT * (vT - meanT) * rsqrtf(varT + 1e-5f) + blT;
        hrow[w][lane] = hS + hT;
        // MLP (lanes 0-31 and 32-63 compute the same j redundantly)
        float a = B1l[j];
        #pragma unroll
        for (int k = 0; k < 64; k++) a += hrow[w][k] * W1l[k * 32 + j];
        a = fmaxf(a, 0.f);
        float p = a * W2l[j];
        #pragma unroll
        for (int o = 16; o >= 1; o >>= 1) p += __shfl_xor(p, o, 32);
        if (lane == 0) out[node] = 1.f / (1.f + expf(-(p + c2)));
    }
}

extern "C" void kernel_launch(void* const* d_in, const int* in_sizes, int n_in,
                              void* d_out, int out_size, void* d_ws, size_t ws_size,
                              hipStream_t stream) {
    const float* x   = (const float*)d_in[0];
    const int*   ei  = (const int*)d_in[1];
    const int*   tei = (const int*)d_in[3];
    const float* sW0 = (const float*)d_in[4],  *sa0 = (const float*)d_in[5];
    const float* sg0 = (const float*)d_in[6],  *sb0 = (const float*)d_in[7];
    const float* sW1 = (const float*)d_in[8],  *sa1 = (const float*)d_in[9];
    const float* sg1 = (const float*)d_in[10], *sb1 = (const float*)d_in[11];
    const float* tW0 = (const float*)d_in[12], *ta0 = (const float*)d_in[13];
    const float* tg0 = (const float*)d_in[14], *tb0 = (const float*)d_in[15];
    const float* tW1 = (const float*)d_in[16], *ta1 = (const float*)d_in[17];
    const float* tg1 = (const float*)d_in[18], *tb1 = (const float*)d_in[19];
    const float* cW1 = (const float*)d_in[20], *cb1 = (const float*)d_in[21];
    const float* cW2 = (const float*)d_in[22], *cb2 = (const float*)d_in[23];
    float* out = (float*)d_out;

    float* ws = (float*)d_ws;
    size_t o = 0;
    float* hS  = ws + o; o += (size_t)NN * HID;   // acc S (aliased across layers)
    float* hT  = ws + o; o += (size_t)NN * HID;   // acc T
    float* WhS = ws + o; o += (size_t)NN * HID;
    float* WhT = ws + o; o += (size_t)NN * HID;
    float* bsumz = ws + o; o += 2 * NBE;
    float* sum_a = ws + o; o += 4;
    int* ip = (int*)(ws + o);
    int* rowptrS = ip; ip += NN + 1;
    int* rowptrT = ip; ip += NN + 1;
    int* csrsS   = ip; ip += NE;
    int* csrsT   = ip; ip += NE;

    // CSR-build scratch aliases WhS/WhT (only live before the layers)
    unsigned* part = (unsigned*)WhS;           // 3.2M packed entries = 12.8 MB
    int*  cnt    = (int*)WhT;                  // MATN
    int*  rowtmp = cnt + (MATN + 1);
    int*  bsum   = rowtmp + MATN;

    const int NSB = (MATN + 1023) / 1024;

    // ---- CSR build (both edge lists, bucket partition) ----
    bucket_hist<<<2 * NBLK, 256, 0, stream>>>(ei, tei, cnt);
    scanA<<<NSB, 256, 0, stream>>>(cnt, rowtmp, bsum, MATN);
    scanB<<<1, 256, 0, stream>>>(bsum, NSB, sa0, sa1, ta0, ta1, sum_a);
    bucket_scatter<<<2 * NBLK, 256, 0, stream>>>(ei, tei, rowtmp, bsum, part);
    bucket_csr<<<2 * NBUCK, 1024, 0, stream>>>(part, rowtmp, bsum,
                                               rowptrS, rowptrT, csrsS, csrsT);

    const int nbh = (NN + 63) / 64;

    // ---- layer 0 (batched S+T) ----
    gemm2_k8<<<2 * nbh, 256, 0, stream>>>(x, sW0, tW0, WhS, WhT, NN);
    edge_agg2<<<2 * NBE, 256, 0, stream>>>(WhS, WhT, rowptrS, rowptrT, csrsS, csrsT,
                                           sum_a, 0, 2, hS, hT, bsumz, NN);
    // L0 norm + L1 GEMM fused
    normgemm2<<<2 * NBG, 256, 0, stream>>>(hS, hT, bsumz,
                                           sg0, sb0, tg0, tb0, sW1, tW1, WhS, WhT, NN);
    // ---- layer 1 (batched S+T) ----
    edge_agg2<<<2 * NBE, 256, 0, stream>>>(WhS, WhT, rowptrS, rowptrT, csrsS, csrsT,
                                           sum_a, 1, 3, hS, hT, bsumz, NN);
    // L1 norm + final MLP fused
    normfinal<<<NBF, 256, 0, stream>>>(hS, hT, bsumz,
                                       sg1, sb1, tg1, tb1, cW1, cb1, cW2, cb2, out, NN);
}